// Round 5
// 221.973 us; speedup vs baseline: 1.0294x; 1.0294x over previous
//
#include <hip/hip_runtime.h>
#include <math.h>

typedef __attribute__((ext_vector_type(8)))  short bf16x8;
typedef __attribute__((ext_vector_type(4)))  float f32x4;
typedef __attribute__((ext_vector_type(16))) float f32x16;
typedef __attribute__((ext_vector_type(2)))  float f32x2;

#define TRI(i,j) (((i)*((i)+1))/2 + (j))
#define ONE3 0.3333333333333333f
#define QOFF 6144   /* Q/R consts after 64*96B frag records */

// RNE f32->bf16 (moment fragments: precision matters)
static __device__ __forceinline__ unsigned short f2b(float f) {
  union { float f; unsigned u; } v; v.f = f;
  unsigned r = v.u + 0x7FFFu + ((v.u >> 16) & 1u);
  return (unsigned short)(r >> 16);
}
static __device__ __forceinline__ unsigned pk2(float lo, float hi) {
  return (unsigned)f2b(lo) | ((unsigned)f2b(hi) << 16);
}
// truncating pack (NN path, dt-damped)
static __device__ __forceinline__ unsigned pk2t(float lo, float hi) {
  return __builtin_amdgcn_perm(__float_as_uint(hi), __float_as_uint(lo), 0x07060302u);
}

// odd deg-7 tanh approx, fitted [-3,3]; no clamp (preactivations bounded, dt-damped)
#define TC0 0.970866f
#define TC1 (-0.217815f)
#define TC2 0.028904f
#define TC3 (-0.0014079f)

static __device__ __forceinline__ unsigned tanh2_pk(float a, float b) {
#if __has_builtin(__builtin_elementwise_fma)
  f32x2 z; z[0] = a; z[1] = b;
  f32x2 k3 = {TC3, TC3}, k2 = {TC2, TC2}, k1 = {TC1, TC1}, k0 = {TC0, TC0};
  f32x2 t = z * z;
  f32x2 p = __builtin_elementwise_fma(t, k3, k2);
  p = __builtin_elementwise_fma(p, t, k1);
  p = __builtin_elementwise_fma(p, t, k0);
  f32x2 r = z * p;
  return pk2t(r[0], r[1]);
#else
  float ta = a * a, tb = b * b;
  float pa = fmaf(fmaf(fmaf(TC3, ta, TC2), ta, TC1), ta, TC0);
  float pb = fmaf(fmaf(fmaf(TC3, tb, TC2), tb, TC1), tb, TC0);
  return pk2t(a * pa, b * pb);
#endif
}

// ---- tiny prep: 1 block / 64 lanes. Packs weight frags + Q/R consts into ws.
// A2 k-slot perm: hidden(kq,u,j) = 32*(kq>>1) + 16*(kq&1) + 4u + (j<4?j:j+4) so each
// lane's D1 C-layout regs Hpk[4kq..4kq+3] ARE the layer-2 B fragment (no exchange).
// A2 m-rows DUPLICATED so both u-halves own all 6 feats in d2 regs 0..5.
__global__ void prep_small(const float* __restrict__ W1, const float* __restrict__ b1,
                           const float* __restrict__ W2,
                           const float* __restrict__ LQ, const float* __restrict__ LR,
                           char* __restrict__ ws) {
  int lane = threadIdx.x;
  if (lane >= 64) return;
  int mr = lane & 31, u = lane >> 5;
  unsigned* A1 = (unsigned*)(ws + lane * 96);
  unsigned* A2 = (unsigned*)(ws + lane * 96 + 32);
#pragma unroll
  for (int t = 0; t < 2; ++t) {
    int h = 32 * t + mr;
    if (u == 0) {
#pragma unroll
      for (int p = 0; p < 4; ++p)
        A1[t * 4 + p] = pk2(W1[(2 * p) * 64 + h], W1[(2 * p + 1) * 64 + h]);
    } else {
      A1[t * 4 + 0] = pk2(b1[h], 0.0f);
      A1[t * 4 + 1] = 0u; A1[t * 4 + 2] = 0u; A1[t * 4 + 3] = 0u;
    }
  }
  int fr = (mr < 4) ? mr
         : (mr < 10) ? (mr - 4)
         : (mr >= 12 && mr < 14) ? (mr - 8) : -1;
#pragma unroll
  for (int kq = 0; kq < 4; ++kq) {
#pragma unroll
    for (int p = 0; p < 4; ++p) {
      int rm = 2 * p + ((p >= 2) ? 4 : 0);
      int hid = 32 * (kq >> 1) + 16 * (kq & 1) + 4 * u + rm;
      float lo = (fr >= 0) ? W2[hid * 6 + fr] : 0.0f;
      float hi = (fr >= 0) ? W2[(hid + 1) * 6 + fr] : 0.0f;
      A2[kq * 4 + p] = pk2(lo, hi);
    }
  }
  if (lane == 0) {
    float* qo = (float*)(ws + QOFF);
    for (int i = 0; i < 6; ++i)
      for (int j = 0; j <= i; ++j) {
        float s = (i == j) ? 1e-7f : 0.0f;
        for (int k = 0; k <= j; ++k) s = fmaf(LQ[i * 6 + k], LQ[j * 6 + k], s);
        qo[TRI(i, j)] = s;
      }
    for (int i = 0; i < 3; ++i)
      for (int j = 0; j <= i; ++j) {
        float s = (i == j) ? 1e-7f : 0.0f;
        for (int k = 0; k <= j; ++k) s = fmaf(LR[i * 3 + k], LR[j * 3 + k], s);
        qo[21 + TRI(i, j)] = s;
      }
  }
}

// ---- fused: cholesky + RK4/NN + moments + kalman epilogue + coalesced output ----
// one wave = 2 batches. NO early return (block-wide barrier before output copy).
// NOTE: __launch_bounds__(256,4) — (256,8) caps VGPR at 64 and spills the K-loop.
__launch_bounds__(256, 4)
__global__ void ukf_fused(const float* __restrict__ gx,
                          const float* __restrict__ gP,
                          const float* __restrict__ gu,
                          const float* __restrict__ gy,
                          const float* __restrict__ gb2,
                          const char*  __restrict__ ws,
                          float* __restrict__ out, int B) {
  __shared__ f32x4 ldsv[4][136];   // per wave: dx[32 cols][17] f32; reused as epi scratch
  __shared__ float outst[912];     // block output staging: xu|Pu|xp|Pp|yp|S|K
  int lane = threadIdx.x & 63;
  int wid  = threadIdx.x >> 6;
  int p    = blockIdx.x * 4 + wid;
  int u    = lane >> 5;
  int c    = lane & 31;
  int q16 = lane >> 4, m16 = lane & 15;
  int bcr = 2 * p + ((lane >> 4) & 1);
  int bc  = (bcr < B) ? bcr : (B - 1);
  float* dxs = (float*)&ldsv[wid][0];

  // sigma column ids
  int   sidx = c & 15;
  float sgn = (sidx == 0 || sidx > 12) ? 0.0f : ((sidx <= 6) ? 1.0f : -1.0f);
  int   cc  = (sidx >= 1 && sidx <= 6) ? (sidx - 1) : ((sidx >= 7) ? (sidx - 7) : 0);
  if (cc > 5) cc = 5;

  // ---- per-lane cholesky of P[bc]; keep only column cc (cndmask chain, no
  //      runtime register-array index -> no scratch) ----
  float Lc[6] = {0.f, 0.f, 0.f, 0.f, 0.f, 0.f};
  {
    float base_[21];
#pragma unroll
    for (int t = 0; t < 21; ++t) base_[t] = 0.0f;
    const float4* p4 = (const float4*)(gP + (size_t)bc * 36);
#pragma unroll
    for (int q = 0; q < 9; ++q) {
      float4 v = p4[q];
      float e0 = v.x, e1 = v.y, e2 = v.z, e3 = v.w;
      float ee[4] = {e0, e1, e2, e3};
#pragma unroll
      for (int r = 0; r < 4; ++r) {
        int idx = q * 4 + r, i = idx / 6, j = idx % 6;        // compile-time
        int a = (i >= j) ? i : j, b2_ = (i >= j) ? j : i;
        base_[TRI(a, b2_)] += ((i == j) ? 1.5f : 0.75f) * ee[r];
      }
    }
#pragma unroll
    for (int i = 0; i < 6; ++i) base_[TRI(i, i)] += 1e-5f;
    float Lt[21];
#pragma unroll
    for (int k = 0; k < 6; ++k) {
      float s = base_[TRI(k, k)];
#pragma unroll
      for (int m2 = 0; m2 < k; ++m2) s = fmaf(-Lt[TRI(k, m2)], Lt[TRI(k, m2)], s);
      float rs = __builtin_amdgcn_rsqf(s);     // s >= 1e-5 (SPD + jitter)
      float d  = s * rs;                        // sqrt(s)
      Lt[TRI(k, k)] = d;
#pragma unroll
      for (int i = k + 1; i < 6; ++i) {
        float s2 = base_[TRI(i, k)];
#pragma unroll
        for (int m2 = 0; m2 < k; ++m2) s2 = fmaf(-Lt[TRI(i, m2)], Lt[TRI(k, m2)], s2);
        Lt[TRI(i, k)] = s2 * rs;
      }
      bool tk = (cc == k);
      Lc[k] = tk ? d : Lc[k];
#pragma unroll
      for (int i = k + 1; i < 6; ++i) Lc[i] = tk ? Lt[TRI(i, k)] : Lc[i];
    }
  }

  float x0c[6];
  {
    const float* xb = gx + (size_t)bc * 6;
    float2 t0 = *(const float2*)(xb);
    float2 t1 = *(const float2*)(xb + 2);
    float2 t2 = *(const float2*)(xb + 4);
    x0c[0]=t0.x; x0c[1]=t0.y; x0c[2]=t1.x; x0c[3]=t1.y; x0c[4]=t2.x; x0c[5]=t2.y;
  }
  float2 uu = *(const float2*)(gu + (size_t)bc * 2);
  unsigned uu_pk = pk2(uu.x, uu.y);

  const char* wp = ws + lane * 96;
  bf16x8 A1v0 = *((const bf16x8*)wp);
  bf16x8 A1v1 = *((const bf16x8*)(wp + 16));
  bf16x8 A2v[4];
#pragma unroll
  for (int kq = 0; kq < 4; ++kq) A2v[kq] = *((const bf16x8*)(wp + 32 + kq * 16));
  float b2r[6];
#pragma unroll
  for (int i = 0; i < 6; ++i) b2r[i] = gb2[i];

  // xs (stage-0 input); fold b2 into bases
  float xs[6], sgnLp[6], xs005[6];
#pragma unroll
  for (int f = 0; f < 6; ++f) {
    float sl = sgn * Lc[f];
    xs[f] = x0c[f] + sl;
    sgnLp[f] = fmaf(0.01f, b2r[f], sl);           // dl base: sgnL + dt*b2
  }
  union { bf16x8 v; unsigned w[4]; } bx;
  bx.w[0] = u ? 0x00003F80u : pk2t(xs[0], xs[1]);
  bx.w[1] = pk2t(xs[2], xs[3]);
  bx.w[2] = pk2t(xs[4], xs[5]);
  bx.w[3] = uu_pk;
#pragma unroll
  for (int f = 0; f < 6; ++f) xs005[f] = fmaf(0.005f, b2r[f], xs[f]);

  f32x16 z16;
#pragma unroll
  for (int i = 0; i < 16; ++i) z16[i] = 0.0f;

  float ksum[6] = {0.f, 0.f, 0.f, 0.f, 0.f, 0.f};
#pragma unroll
  for (int st = 0; st < 4; ++st) {
    f32x16 d1a = __builtin_amdgcn_mfma_f32_32x32x16_bf16(A1v0, bx.v, z16, 0, 0, 0);
    f32x16 d1b = __builtin_amdgcn_mfma_f32_32x32x16_bf16(A1v1, bx.v, z16, 0, 0, 0);
    unsigned Hpk[16];
#pragma unroll
    for (int pr = 0; pr < 8; ++pr) Hpk[pr]     = tanh2_pk(d1a[2*pr], d1a[2*pr+1]);
#pragma unroll
    for (int pr = 0; pr < 8; ++pr) Hpk[8 + pr] = tanh2_pk(d1b[2*pr], d1b[2*pr+1]);
    // layer2: B-fragment = own Hpk[4kq..4kq+3]; A has duplicated feat rows
    f32x16 d2 = z16;
#pragma unroll
    for (int kq = 0; kq < 4; ++kq) {
      union { bf16x8 v; unsigned w[4]; } bh;
      bh.w[0] = Hpk[4*kq+0]; bh.w[1] = Hpk[4*kq+1];
      bh.w[2] = Hpk[4*kq+2]; bh.w[3] = Hpk[4*kq+3];
      d2 = __builtin_amdgcn_mfma_f32_32x32x16_bf16(A2v[kq], bh.v, d2, 0, 0, 0);
    }
    const float wks = (st == 0 || st == 3) ? 1.0f : 2.0f;
#pragma unroll
    for (int f = 0; f < 6; ++f) ksum[f] = fmaf(wks, d2[f], ksum[f]);
    if (st < 3) {
      const float cin = (st == 2) ? 0.01f : 0.005f;
      float xi[6];
#pragma unroll
      for (int f = 0; f < 6; ++f) {
        float basef = (st == 2) ? fmaf(0.005f, b2r[f], xs005[f]) : xs005[f];
        xi[f] = fmaf(cin, d2[f], basef);
      }
      bx.w[0] = u ? 0x00003F80u : pk2t(xi[0], xi[1]);
      bx.w[1] = pk2t(xi[2], xi[3]);
      bx.w[2] = pk2t(xi[4], xi[5]);
    }
  }

  // deltas -> LDS (stride 17, conflict-free); both halves identical, u==0 writes
  const float dt6 = 0.01f / 6.0f;
  if (u == 0) {
#pragma unroll
    for (int f = 0; f < 6; ++f) dxs[c * 17 + f] = fmaf(dt6, ksum[f], sgnLp[f]);
  }

  // ---- moments: two 16x16x32 MFMAs, shared B = dx ----
  float dxv[8];
#pragma unroll
  for (int j = 0; j < 8; ++j) dxv[j] = dxs[(8 * q16 + j) * 17 + m16];
  float wc0[8], wc1[8];
#pragma unroll
  for (int j = 0; j < 8; ++j) {
    float c0j = (j == 0) ? -0.25f : ONE3;
    float c1j = (j <= 4) ? ONE3 : 0.0f;
    wc0[j] = (q16 == 0) ? c0j : ((q16 == 1) ? c1j : 0.0f);
    wc1[j] = (q16 == 2) ? c0j : ((q16 == 3) ? c1j : 0.0f);
  }
  float wm00 = (q16 == 0) ? -3.0f : wc0[0];
  float wm10 = (q16 == 2) ? -3.0f : wc1[0];
  bool mlt6 = (m16 < 6), m6 = (m16 == 6), m7 = (m16 == 7);
  union { bf16x8 v; unsigned w[4]; } am0, am1, bw;
  {
    float a0[8], a1[8];
#pragma unroll
    for (int j = 0; j < 8; ++j) {
      float wmj0 = (j == 0) ? wm00 : wc0[j];
      float wmj1 = (j == 0) ? wm10 : wc1[j];
      float alt0 = m6 ? wc0[j] : (m7 ? wmj0 : 0.0f);
      float alt1 = m6 ? wc1[j] : (m7 ? wmj1 : 0.0f);
      a0[j] = mlt6 ? wc0[j] * dxv[j] : alt0;
      a1[j] = mlt6 ? wc1[j] * dxv[j] : alt1;
    }
#pragma unroll
    for (int pr = 0; pr < 4; ++pr) {
      am0.w[pr] = pk2(a0[2*pr], a0[2*pr+1]);
      am1.w[pr] = pk2(a1[2*pr], a1[2*pr+1]);
      bw.w[pr]  = pk2(dxv[2*pr], dxv[2*pr+1]);
    }
  }
  f32x4 zz = {0.0f, 0.0f, 0.0f, 0.0f};
  f32x4 Dm0 = __builtin_amdgcn_mfma_f32_16x16x32_bf16(am0.v, bw.v, zz, 0, 0, 0);
  f32x4 Dm1 = __builtin_amdgcn_mfma_f32_16x16x32_bf16(am1.v, bw.v, zz, 0, 0, 0);

  // ---- stage U (rows 0..5 = moment matrix, row 6 = cb, row 7 = db) into the
  //      wave's dx region (dead after dxv loads). wave-synchronous LDS. ----
  float* Uw  = dxs;          // [2][48]
  float* Dw  = dxs + 96;     // [2][24]
  float* Kw  = dxs + 144;    // [2][20]
  float* KSw = dxs + 184;    // [2][20]
  if (q16 < 2 && m16 < 6) {
#pragma unroll
    for (int i = 0; i < 4; ++i) {
      Uw[(4 * q16 + i) * 6 + m16]      = Dm0[i];
      Uw[48 + (4 * q16 + i) * 6 + m16] = Dm1[i];
    }
  }

  // ---- fused epilogue: half-wave u owns batch 2p+u, 32 lanes parallel ----
  int el = c;
  int bEr = 2 * p + u;
  int bE  = (bEr < B) ? bEr : (B - 1);
  bool ebA = (bEr < B);
  const float* qro = (const float*)(ws + QOFF);
  const float* xbE = gx + (size_t)bE * 6;
  const float* ybE = gy + (size_t)bE * 3;

  // xp[0..2] for innovation (runtime-free register indices)
  float xp0 = xbE[0] + Uw[u * 48 + 42];
  float xp1 = xbE[1] + Uw[u * 48 + 43];
  float xp2 = xbE[2] + Uw[u * 48 + 44];
  float i0 = ybE[0] - xp0, i1 = ybE[1] - xp1, i2 = ybE[2] - xp2;

  // D(i,j) = U - cb_i db_j - db_i cb_j + 3.75 db_i db_j   (21 lanes)
  int ti = (el >= 15) ? 5 : (el >= 10) ? 4 : (el >= 6) ? 3 : (el >= 3) ? 2 : (el >= 1) ? 1 : 0;
  int tj = el - (ti * (ti + 1)) / 2;
  if (el < 21) {
    float Uv  = Uw[u * 48 + ti * 6 + tj];
    float cbi = Uw[u * 48 + 36 + ti], cbj = Uw[u * 48 + 36 + tj];
    float dbi = Uw[u * 48 + 42 + ti], dbj = Uw[u * 48 + 42 + tj];
    float v = Uv - cbi * dbj - dbi * cbj;
    v = fmaf(3.75f * dbi, dbj, v);
    Dw[u * 24 + el] = v;
  }
  float D0 = Dw[u*24+0], D1 = Dw[u*24+1], D2 = Dw[u*24+2];
  float D3 = Dw[u*24+3], D4 = Dw[u*24+4], D5 = Dw[u*24+5];
  // S = D[:3,:3] + R ; inverse redundant on all lanes
  float s00 = D0 + qro[21], s10 = D1 + qro[22], s11 = D2 + qro[23];
  float s20 = D3 + qro[24], s21 = D4 + qro[25], s22 = D5 + qro[26];
  float a00 = s00 + 1e-5f, a11 = s11 + 1e-5f, a22 = s22 + 1e-5f;
  float a10 = s10, a20 = s20, a21 = s21;
  float adj00 = a11*a22 - a21*a21;
  float adj01 = a20*a21 - a10*a22;
  float adj02 = a10*a21 - a11*a20;
  float adj11 = a00*a22 - a20*a20;
  float adj12 = a10*a20 - a00*a21;
  float adj22 = a00*a11 - a10*a10;
  float det  = a00*adj00 + a10*adj01 + a20*adj02;
  float idet = __builtin_amdgcn_rcpf(det);
  float I00 = adj00*idet, I01 = adj01*idet, I02 = adj02*idet;
  float I11 = adj11*idet, I12 = adj12*idet, I22 = adj22*idet;

  int ki = el / 3, kj = el - 3 * ki;     // const-divisor magic mul
  if (el < 18) {                          // K = cross * S_inv   (18 lanes)
    int tb = (ki * (ki + 1)) / 2;
    float c0 = Dw[u * 24 + tb];
    float c1 = Dw[u * 24 + ((ki >= 1) ? (tb + 1) : 1)];
    float c2 = Dw[u * 24 + ((ki >= 2) ? (tb + 2) : (3 + ki))];
    float w0 = (kj == 0) ? I00 : ((kj == 1) ? I01 : I02);
    float w1 = (kj == 0) ? I01 : ((kj == 1) ? I11 : I12);
    float w2 = (kj == 0) ? I02 : ((kj == 1) ? I12 : I22);
    Kw[u * 20 + el] = c0 * w0 + c1 * w1 + c2 * w2;
  }
  if (el < 18) {                          // KS = K * S
    float k0 = Kw[u * 20 + ki * 3], k1 = Kw[u * 20 + ki * 3 + 1], k2 = Kw[u * 20 + ki * 3 + 2];
    float S0 = (kj == 0) ? s00 : ((kj == 1) ? s10 : s20);
    float S1 = (kj == 0) ? s10 : ((kj == 1) ? s11 : s21);
    float S2 = (kj == 0) ? s20 : ((kj == 1) ? s21 : s22);
    KSw[u * 20 + el] = k0 * S0 + k1 * S1 + k2 * S2;
  }

  int s = wid * 2 + u;                    // slot 0..7 == batch bbase+s
  if (el < 6) {                           // xu / xp / yp
    float dbl = Uw[u * 48 + 42 + el];
    float xpl = xbE[el] + dbl;
    float k0 = Kw[u * 20 + el * 3], k1 = Kw[u * 20 + el * 3 + 1], k2 = Kw[u * 20 + el * 3 + 2];
    float xuv = xpl + k0 * i0 + k1 * i1 + k2 * i2;
    if (ebA) {
      outst[0   + s * 6 + el] = xuv;
      outst[336 + s * 6 + el] = xpl;
      if (el < 3) outst[672 + s * 3 + el] = xpl;
    }
  }
  if (el < 9 && ebA) {                    // S full 3x3
    int si = (el >= 6) ? 2 : (el >= 3) ? 1 : 0;
    int sj = el - 3 * si;
    int aa = (si > sj) ? si : sj, bb = (si > sj) ? sj : si;
    int ab = (aa * (aa + 1)) / 2 + bb;
    float sv = (ab == 0) ? s00 : (ab == 1) ? s10 : (ab == 2) ? s11
             : (ab == 3) ? s20 : (ab == 4) ? s21 : s22;
    outst[696 + s * 9 + el] = sv;
  }
  if (el < 18 && ebA) outst[768 + s * 18 + el] = Kw[u * 20 + el];
  if (el < 21) {                          // Pu (and Pp = D + Q), symmetric fill
    float Dv = Dw[u * 24 + el];
    float Qv = qro[el];
    float ks0 = KSw[u * 20 + ti * 3], ks1 = KSw[u * 20 + ti * 3 + 1], ks2 = KSw[u * 20 + ti * 3 + 2];
    float kj0 = Kw[u * 20 + tj * 3],  kj1 = Kw[u * 20 + tj * 3 + 1],  kj2 = Kw[u * 20 + tj * 3 + 2];
    float pu = Dv + Qv - (ks0 * kj0 + ks1 * kj1 + ks2 * kj2) + ((ti == tj) ? 1e-4f : 0.0f);
    float pp = Dv + Qv;
    if (ebA) {
      outst[48  + s * 36 + ti * 6 + tj] = pu;
      outst[48  + s * 36 + tj * 6 + ti] = pu;
      outst[384 + s * 36 + ti * 6 + tj] = pp;
      outst[384 + s * 36 + tj * 6 + ti] = pp;
    }
  }

  __syncthreads();

  // ---- cooperative coalesced output copy: 228 float4 / block ----
  int bbase = blockIdx.x * 8;
  float* o_xu = out;
  float* o_Pu = out + (size_t)6  * B;
  float* o_xp = out + (size_t)42 * B;
  float* o_Pp = out + (size_t)48 * B;
  float* o_yp = out + (size_t)84 * B;
  float* o_S  = out + (size_t)87 * B;
  float* o_K  = out + (size_t)96 * B;
  int t = threadIdx.x;
  if (bbase + 8 <= B && (B & 3) == 0) {   // fast path: all segment bases f4-aligned
    if (t < 228) {
      const float4* ls = (const float4*)outst;
      float4 v = ls[t];
      float4* gp;
      if      (t < 12)  gp = (float4*)(o_xu + (size_t)bbase * 6)  + t;
      else if (t < 84)  gp = (float4*)(o_Pu + (size_t)bbase * 36) + (t - 12);
      else if (t < 96)  gp = (float4*)(o_xp + (size_t)bbase * 6)  + (t - 84);
      else if (t < 168) gp = (float4*)(o_Pp + (size_t)bbase * 36) + (t - 96);
      else if (t < 174) gp = (float4*)(o_yp + (size_t)bbase * 3)  + (t - 168);
      else if (t < 192) gp = (float4*)(o_S  + (size_t)bbase * 9)  + (t - 174);
      else              gp = (float4*)(o_K  + (size_t)bbase * 18) + (t - 192);
      *gp = v;
    }
  } else {                                 // tail block: per-float, bounds-checked
    for (int e = t; e < 912; e += 256) {
      float val = outst[e];
      int r = e, slot; float* gp;
      if (r < 48)        {            slot = r / 6;  gp = o_xu + (size_t)(bbase + slot) * 6  + (r - slot * 6);  }
      else if (r < 336)  { r -= 48;   slot = r / 36; gp = o_Pu + (size_t)(bbase + slot) * 36 + (r - slot * 36); }
      else if (r < 384)  { r -= 336;  slot = r / 6;  gp = o_xp + (size_t)(bbase + slot) * 6  + (r - slot * 6);  }
      else if (r < 672)  { r -= 384;  slot = r / 36; gp = o_Pp + (size_t)(bbase + slot) * 36 + (r - slot * 36); }
      else if (r < 696)  { r -= 672;  slot = r / 3;  gp = o_yp + (size_t)(bbase + slot) * 3  + (r - slot * 3);  }
      else if (r < 768)  { r -= 696;  slot = r / 9;  gp = o_S  + (size_t)(bbase + slot) * 9  + (r - slot * 9);  }
      else               { r -= 768;  slot = r / 18; gp = o_K  + (size_t)(bbase + slot) * 18 + (r - slot * 18); }
      if (bbase + slot < B) *gp = val;
    }
  }
}

extern "C" void kernel_launch(void* const* d_in, const int* in_sizes, int n_in,
                              void* d_out, int out_size, void* d_ws, size_t ws_size,
                              hipStream_t stream) {
  const float* x  = (const float*)d_in[0];
  const float* P  = (const float*)d_in[1];
  const float* u  = (const float*)d_in[2];
  const float* y  = (const float*)d_in[3];
  const float* LQ = (const float*)d_in[4];
  const float* LR = (const float*)d_in[5];
  const float* W1 = (const float*)d_in[6];
  const float* b1 = (const float*)d_in[7];
  const float* W2 = (const float*)d_in[8];
  const float* b2 = (const float*)d_in[9];
  float* out = (float*)d_out;
  char*  ws  = (char*)d_ws;
  int B = in_sizes[0] / 6;

  hipLaunchKernelGGL(prep_small, dim3(1), dim3(64), 0, stream,
                     W1, b1, W2, LQ, LR, ws);
  hipLaunchKernelGGL(ukf_fused, dim3((B + 7) / 8), dim3(256), 0, stream,
                     x, P, u, y, b2, (const char*)ws, out, B);
}

// Round 10
// 218.619 us; speedup vs baseline: 1.0452x; 1.0153x over previous
//
#include <hip/hip_runtime.h>
#include <math.h>

typedef __attribute__((ext_vector_type(8)))  short bf16x8;
typedef __attribute__((ext_vector_type(4)))  float f32x4;
typedef __attribute__((ext_vector_type(16))) float f32x16;
typedef __attribute__((ext_vector_type(2)))  float f32x2;

#define TRI(i,j) (((i)*((i)+1))/2 + (j))
#define ONE3 0.3333333333333333f
#define QOFF 6144   /* Q/R consts after 64*96B frag records */

// RNE f32->bf16 (prep only; main kernel uses v_cvt_pk_bf16_f32)
static __device__ __forceinline__ unsigned short f2b(float f) {
  union { float f; unsigned u; } v; v.f = f;
  unsigned r = v.u + 0x7FFFu + ((v.u >> 16) & 1u);
  return (unsigned short)(r >> 16);
}
static __device__ __forceinline__ unsigned pk2(float lo, float hi) {
  return (unsigned)f2b(lo) | ((unsigned)f2b(hi) << 16);
}
// truncating pack (NN path, dt-damped)
static __device__ __forceinline__ unsigned pk2t(float lo, float hi) {
  return __builtin_amdgcn_perm(__float_as_uint(hi), __float_as_uint(lo), 0x07060302u);
}

// HW RNE pack: 2 f32 -> 1 u32 of 2 bf16 (1 instr vs ~9 for manual RNE) [T12/m240]
static __device__ __forceinline__ unsigned cvtpk(float lo, float hi) {
  unsigned d;
  asm("v_cvt_pk_bf16_f32 %0, %1, %2" : "=v"(d) : "v"(lo), "v"(hi));
  return d;
}
// forced VOP3P packed-f32 math (compiler does not reliably emit v_pk_* for f32x2)
static __device__ __forceinline__ f32x2 pk_mul(f32x2 a, f32x2 b) {
  f32x2 d;
  asm("v_pk_mul_f32 %0, %1, %2" : "=v"(d) : "v"(a), "v"(b));
  return d;
}
static __device__ __forceinline__ f32x2 pk_fma(f32x2 a, f32x2 b, f32x2 c) {
  f32x2 d;
  asm("v_pk_fma_f32 %0, %1, %2, %3" : "=v"(d) : "v"(a), "v"(b), "v"(c));
  return d;
}

// odd deg-7 tanh approx, fitted [-3,3]; no clamp (preactivations bounded, dt-damped)
#define TC0 0.970866f
#define TC1 (-0.217815f)
#define TC2 0.028904f
#define TC3 (-0.0014079f)

// packed tanh pair: 2 pk_mul + 3 pk_fma + 1 perm = 6 instr / 2 values
static __device__ __forceinline__ unsigned tanh2_pk(float a, float b) {
  f32x2 z; z[0] = a; z[1] = b;
  const f32x2 k3 = {TC3, TC3}, k2 = {TC2, TC2}, k1 = {TC1, TC1}, k0 = {TC0, TC0};
  f32x2 t = pk_mul(z, z);
  f32x2 p = pk_fma(t, k3, k2);
  p = pk_fma(p, t, k1);
  p = pk_fma(p, t, k0);
  f32x2 r = pk_mul(z, p);
  return pk2t(r[0], r[1]);
}

// ---- tiny prep: 1 block / 64 lanes. Packs weight frags + Q/R consts into ws.
// A2 k-slot perm: hidden(kq,u,j) = 32*(kq>>1) + 16*(kq&1) + 4u + (j<4?j:j+4) so each
// lane's D1 C-layout regs Hpk[4kq..4kq+3] ARE the layer-2 B fragment (no exchange).
// A2 m-rows DUPLICATED so both u-halves own all 6 feats in d2 regs 0..5.
__global__ void prep_small(const float* __restrict__ W1, const float* __restrict__ b1,
                           const float* __restrict__ W2,
                           const float* __restrict__ LQ, const float* __restrict__ LR,
                           char* __restrict__ ws) {
  int lane = threadIdx.x;
  if (lane >= 64) return;
  int mr = lane & 31, u = lane >> 5;
  unsigned* A1 = (unsigned*)(ws + lane * 96);
  unsigned* A2 = (unsigned*)(ws + lane * 96 + 32);
#pragma unroll
  for (int t = 0; t < 2; ++t) {
    int h = 32 * t + mr;
    if (u == 0) {
#pragma unroll
      for (int p = 0; p < 4; ++p)
        A1[t * 4 + p] = pk2(W1[(2 * p) * 64 + h], W1[(2 * p + 1) * 64 + h]);
    } else {
      A1[t * 4 + 0] = pk2(b1[h], 0.0f);
      A1[t * 4 + 1] = 0u; A1[t * 4 + 2] = 0u; A1[t * 4 + 3] = 0u;
    }
  }
  int fr = (mr < 4) ? mr
         : (mr < 10) ? (mr - 4)
         : (mr >= 12 && mr < 14) ? (mr - 8) : -1;
#pragma unroll
  for (int kq = 0; kq < 4; ++kq) {
#pragma unroll
    for (int p = 0; p < 4; ++p) {
      int rm = 2 * p + ((p >= 2) ? 4 : 0);
      int hid = 32 * (kq >> 1) + 16 * (kq & 1) + 4 * u + rm;
      float lo = (fr >= 0) ? W2[hid * 6 + fr] : 0.0f;
      float hi = (fr >= 0) ? W2[(hid + 1) * 6 + fr] : 0.0f;
      A2[kq * 4 + p] = pk2(lo, hi);
    }
  }
  if (lane == 0) {
    float* qo = (float*)(ws + QOFF);
    for (int i = 0; i < 6; ++i)
      for (int j = 0; j <= i; ++j) {
        float s = (i == j) ? 1e-7f : 0.0f;
        for (int k = 0; k <= j; ++k) s = fmaf(LQ[i * 6 + k], LQ[j * 6 + k], s);
        qo[TRI(i, j)] = s;
      }
    for (int i = 0; i < 3; ++i)
      for (int j = 0; j <= i; ++j) {
        float s = (i == j) ? 1e-7f : 0.0f;
        for (int k = 0; k <= j; ++k) s = fmaf(LR[i * 3 + k], LR[j * 3 + k], s);
        qo[21 + TRI(i, j)] = s;
      }
  }
}

// ---- fused: cholesky + RK4/NN + moments + kalman epilogue + coalesced output ----
// one wave = 2 batches. NO early return (block-wide barrier before output copy).
// NOTE: __launch_bounds__(256,4) — (256,8) caps VGPR at 64 and spills the K-loop.
__launch_bounds__(256, 4)
__global__ void ukf_fused(const float* __restrict__ gx,
                          const float* __restrict__ gP,
                          const float* __restrict__ gu,
                          const float* __restrict__ gy,
                          const float* __restrict__ gb2,
                          const char*  __restrict__ ws,
                          float* __restrict__ out, int B) {
  __shared__ f32x4 ldsv[4][136];   // per wave: dx[32 cols][17] f32; reused as epi scratch
  __shared__ float outst[912];     // block output staging: xu|Pu|xp|Pp|yp|S|K
  int lane = threadIdx.x & 63;
  int wid  = threadIdx.x >> 6;
  int p    = blockIdx.x * 4 + wid;
  int u    = lane >> 5;
  int c    = lane & 31;
  int q16 = lane >> 4, m16 = lane & 15;
  int bcr = 2 * p + ((lane >> 4) & 1);
  int bc  = (bcr < B) ? bcr : (B - 1);
  float* dxs = (float*)&ldsv[wid][0];

  // sigma column ids
  int   sidx = c & 15;
  float sgn = (sidx == 0 || sidx > 12) ? 0.0f : ((sidx <= 6) ? 1.0f : -1.0f);
  int   cc  = (sidx >= 1 && sidx <= 6) ? (sidx - 1) : ((sidx >= 7) ? (sidx - 7) : 0);
  if (cc > 5) cc = 5;

  // ---- per-lane cholesky of P[bc]; keep only column cc (cndmask chain, no
  //      runtime register-array index -> no scratch) ----
  float Lc[6] = {0.f, 0.f, 0.f, 0.f, 0.f, 0.f};
  {
    float base_[21];
#pragma unroll
    for (int t = 0; t < 21; ++t) base_[t] = 0.0f;
    const float4* p4 = (const float4*)(gP + (size_t)bc * 36);
#pragma unroll
    for (int q = 0; q < 9; ++q) {
      float4 v = p4[q];
      float e0 = v.x, e1 = v.y, e2 = v.z, e3 = v.w;
      float ee[4] = {e0, e1, e2, e3};
#pragma unroll
      for (int r = 0; r < 4; ++r) {
        int idx = q * 4 + r, i = idx / 6, j = idx % 6;        // compile-time
        int a = (i >= j) ? i : j, b2_ = (i >= j) ? j : i;
        base_[TRI(a, b2_)] += ((i == j) ? 1.5f : 0.75f) * ee[r];
      }
    }
#pragma unroll
    for (int i = 0; i < 6; ++i) base_[TRI(i, i)] += 1e-5f;
    float Lt[21];
#pragma unroll
    for (int k = 0; k < 6; ++k) {
      float s = base_[TRI(k, k)];
#pragma unroll
      for (int m2 = 0; m2 < k; ++m2) s = fmaf(-Lt[TRI(k, m2)], Lt[TRI(k, m2)], s);
      float rs = __builtin_amdgcn_rsqf(s);     // s >= 1e-5 (SPD + jitter)
      float d  = s * rs;                        // sqrt(s)
      Lt[TRI(k, k)] = d;
#pragma unroll
      for (int i = k + 1; i < 6; ++i) {
        float s2 = base_[TRI(i, k)];
#pragma unroll
        for (int m2 = 0; m2 < k; ++m2) s2 = fmaf(-Lt[TRI(i, m2)], Lt[TRI(k, m2)], s2);
        Lt[TRI(i, k)] = s2 * rs;
      }
      bool tk = (cc == k);
      Lc[k] = tk ? d : Lc[k];
#pragma unroll
      for (int i = k + 1; i < 6; ++i) Lc[i] = tk ? Lt[TRI(i, k)] : Lc[i];
    }
  }

  float x0c[6];
  {
    const float* xb = gx + (size_t)bc * 6;
    float2 t0 = *(const float2*)(xb);
    float2 t1 = *(const float2*)(xb + 2);
    float2 t2 = *(const float2*)(xb + 4);
    x0c[0]=t0.x; x0c[1]=t0.y; x0c[2]=t1.x; x0c[3]=t1.y; x0c[4]=t2.x; x0c[5]=t2.y;
  }
  float2 uu = *(const float2*)(gu + (size_t)bc * 2);
  unsigned uu_pk = cvtpk(uu.x, uu.y);

  const char* wp = ws + lane * 96;
  bf16x8 A1v0 = *((const bf16x8*)wp);
  bf16x8 A1v1 = *((const bf16x8*)(wp + 16));
  bf16x8 A2v[4];
#pragma unroll
  for (int kq = 0; kq < 4; ++kq) A2v[kq] = *((const bf16x8*)(wp + 32 + kq * 16));
  float b2r[6];
#pragma unroll
  for (int i = 0; i < 6; ++i) b2r[i] = gb2[i];

  // xs (stage-0 input); fold b2 into bases
  float xs[6], sgnLp[6], xs005[6];
#pragma unroll
  for (int f = 0; f < 6; ++f) {
    float sl = sgn * Lc[f];
    xs[f] = x0c[f] + sl;
    sgnLp[f] = fmaf(0.01f, b2r[f], sl);           // dl base: sgnL + dt*b2
  }
  union { bf16x8 v; unsigned w[4]; } bx;
  bx.w[0] = u ? 0x00003F80u : pk2t(xs[0], xs[1]);
  bx.w[1] = pk2t(xs[2], xs[3]);
  bx.w[2] = pk2t(xs[4], xs[5]);
  bx.w[3] = uu_pk;
#pragma unroll
  for (int f = 0; f < 6; ++f) xs005[f] = fmaf(0.005f, b2r[f], xs[f]);

  f32x16 z16;
#pragma unroll
  for (int i = 0; i < 16; ++i) z16[i] = 0.0f;

  float ksum[6] = {0.f, 0.f, 0.f, 0.f, 0.f, 0.f};
#pragma unroll
  for (int st = 0; st < 4; ++st) {
    f32x16 d1a = __builtin_amdgcn_mfma_f32_32x32x16_bf16(A1v0, bx.v, z16, 0, 0, 0);
    f32x16 d1b = __builtin_amdgcn_mfma_f32_32x32x16_bf16(A1v1, bx.v, z16, 0, 0, 0);
    unsigned Hpk[16];
#pragma unroll
    for (int pr = 0; pr < 8; ++pr) Hpk[pr]     = tanh2_pk(d1a[2*pr], d1a[2*pr+1]);
#pragma unroll
    for (int pr = 0; pr < 8; ++pr) Hpk[8 + pr] = tanh2_pk(d1b[2*pr], d1b[2*pr+1]);
    // layer2: B-fragment = own Hpk[4kq..4kq+3]; A has duplicated feat rows
    f32x16 d2 = z16;
#pragma unroll
    for (int kq = 0; kq < 4; ++kq) {
      union { bf16x8 v; unsigned w[4]; } bh;
      bh.w[0] = Hpk[4*kq+0]; bh.w[1] = Hpk[4*kq+1];
      bh.w[2] = Hpk[4*kq+2]; bh.w[3] = Hpk[4*kq+3];
      d2 = __builtin_amdgcn_mfma_f32_32x32x16_bf16(A2v[kq], bh.v, d2, 0, 0, 0);
    }
    const float wks = (st == 0 || st == 3) ? 1.0f : 2.0f;
#pragma unroll
    for (int f = 0; f < 6; ++f) ksum[f] = fmaf(wks, d2[f], ksum[f]);
    if (st < 3) {
      const float cin = (st == 2) ? 0.01f : 0.005f;
      float xi[6];
#pragma unroll
      for (int f = 0; f < 6; ++f) {
        float basef = (st == 2) ? fmaf(0.005f, b2r[f], xs005[f]) : xs005[f];
        xi[f] = fmaf(cin, d2[f], basef);
      }
      bx.w[0] = u ? 0x00003F80u : pk2t(xi[0], xi[1]);
      bx.w[1] = pk2t(xi[2], xi[3]);
      bx.w[2] = pk2t(xi[4], xi[5]);
    }
  }

  // deltas -> LDS (stride 17, conflict-free); both halves identical, u==0 writes
  const float dt6 = 0.01f / 6.0f;
  if (u == 0) {
#pragma unroll
    for (int f = 0; f < 6; ++f) dxs[c * 17 + f] = fmaf(dt6, ksum[f], sgnLp[f]);
  }

  // ---- moments: two 16x16x32 MFMAs, shared B = dx ----
  float dxv[8];
#pragma unroll
  for (int j = 0; j < 8; ++j) dxv[j] = dxs[(8 * q16 + j) * 17 + m16];
  float wc0[8], wc1[8];
#pragma unroll
  for (int j = 0; j < 8; ++j) {
    float c0j = (j == 0) ? -0.25f : ONE3;
    float c1j = (j <= 4) ? ONE3 : 0.0f;
    wc0[j] = (q16 == 0) ? c0j : ((q16 == 1) ? c1j : 0.0f);
    wc1[j] = (q16 == 2) ? c0j : ((q16 == 3) ? c1j : 0.0f);
  }
  float wm00 = (q16 == 0) ? -3.0f : wc0[0];
  float wm10 = (q16 == 2) ? -3.0f : wc1[0];
  bool mlt6 = (m16 < 6), m6 = (m16 == 6), m7 = (m16 == 7);
  union { bf16x8 v; unsigned w[4]; } am0, am1, bw;
  {
    float a0[8], a1[8];
#pragma unroll
    for (int j = 0; j < 8; ++j) {
      float wmj0 = (j == 0) ? wm00 : wc0[j];
      float wmj1 = (j == 0) ? wm10 : wc1[j];
      float alt0 = m6 ? wc0[j] : (m7 ? wmj0 : 0.0f);
      float alt1 = m6 ? wc1[j] : (m7 ? wmj1 : 0.0f);
      a0[j] = mlt6 ? wc0[j] * dxv[j] : alt0;
      a1[j] = mlt6 ? wc1[j] * dxv[j] : alt1;
    }
#pragma unroll
    for (int pr = 0; pr < 4; ++pr) {
      am0.w[pr] = cvtpk(a0[2*pr], a0[2*pr+1]);
      am1.w[pr] = cvtpk(a1[2*pr], a1[2*pr+1]);
      bw.w[pr]  = cvtpk(dxv[2*pr], dxv[2*pr+1]);
    }
  }
  f32x4 zz = {0.0f, 0.0f, 0.0f, 0.0f};
  f32x4 Dm0 = __builtin_amdgcn_mfma_f32_16x16x32_bf16(am0.v, bw.v, zz, 0, 0, 0);
  f32x4 Dm1 = __builtin_amdgcn_mfma_f32_16x16x32_bf16(am1.v, bw.v, zz, 0, 0, 0);

  // ---- stage U (rows 0..5 = moment matrix, row 6 = cb, row 7 = db) into the
  //      wave's dx region (dead after dxv loads). wave-synchronous LDS. ----
  float* Uw  = dxs;          // [2][48]
  float* Dw  = dxs + 96;     // [2][24]
  float* Kw  = dxs + 144;    // [2][20]
  float* KSw = dxs + 184;    // [2][20]
  if (q16 < 2 && m16 < 6) {
#pragma unroll
    for (int i = 0; i < 4; ++i) {
      Uw[(4 * q16 + i) * 6 + m16]      = Dm0[i];
      Uw[48 + (4 * q16 + i) * 6 + m16] = Dm1[i];
    }
  }

  // ---- fused epilogue: half-wave u owns batch 2p+u, 32 lanes parallel ----
  int el = c;
  int bEr = 2 * p + u;
  int bE  = (bEr < B) ? bEr : (B - 1);
  bool ebA = (bEr < B);
  const float* qro = (const float*)(ws + QOFF);
  const float* xbE = gx + (size_t)bE * 6;
  const float* ybE = gy + (size_t)bE * 3;

  // xp[0..2] for innovation (runtime-free register indices)
  float xp0 = xbE[0] + Uw[u * 48 + 42];
  float xp1 = xbE[1] + Uw[u * 48 + 43];
  float xp2 = xbE[2] + Uw[u * 48 + 44];
  float i0 = ybE[0] - xp0, i1 = ybE[1] - xp1, i2 = ybE[2] - xp2;

  // D(i,j) = U - cb_i db_j - db_i cb_j + 3.75 db_i db_j   (21 lanes)
  int ti = (el >= 15) ? 5 : (el >= 10) ? 4 : (el >= 6) ? 3 : (el >= 3) ? 2 : (el >= 1) ? 1 : 0;
  int tj = el - (ti * (ti + 1)) / 2;
  if (el < 21) {
    float Uv  = Uw[u * 48 + ti * 6 + tj];
    float cbi = Uw[u * 48 + 36 + ti], cbj = Uw[u * 48 + 36 + tj];
    float dbi = Uw[u * 48 + 42 + ti], dbj = Uw[u * 48 + 42 + tj];
    float v = Uv - cbi * dbj - dbi * cbj;
    v = fmaf(3.75f * dbi, dbj, v);
    Dw[u * 24 + el] = v;
  }
  float D0 = Dw[u*24+0], D1 = Dw[u*24+1], D2 = Dw[u*24+2];
  float D3 = Dw[u*24+3], D4 = Dw[u*24+4], D5 = Dw[u*24+5];
  // S = D[:3,:3] + R ; inverse redundant on all lanes
  float s00 = D0 + qro[21], s10 = D1 + qro[22], s11 = D2 + qro[23];
  float s20 = D3 + qro[24], s21 = D4 + qro[25], s22 = D5 + qro[26];
  float a00 = s00 + 1e-5f, a11 = s11 + 1e-5f, a22 = s22 + 1e-5f;
  float a10 = s10, a20 = s20, a21 = s21;
  float adj00 = a11*a22 - a21*a21;
  float adj01 = a20*a21 - a10*a22;
  float adj02 = a10*a21 - a11*a20;
  float adj11 = a00*a22 - a20*a20;
  float adj12 = a10*a20 - a00*a21;
  float adj22 = a00*a11 - a10*a10;
  float det  = a00*adj00 + a10*adj01 + a20*adj02;
  float idet = __builtin_amdgcn_rcpf(det);
  float I00 = adj00*idet, I01 = adj01*idet, I02 = adj02*idet;
  float I11 = adj11*idet, I12 = adj12*idet, I22 = adj22*idet;

  int ki = el / 3, kj = el - 3 * ki;     // const-divisor magic mul
  if (el < 18) {                          // K = cross * S_inv   (18 lanes)
    int tb = (ki * (ki + 1)) / 2;
    float c0 = Dw[u * 24 + tb];
    float c1 = Dw[u * 24 + ((ki >= 1) ? (tb + 1) : 1)];
    float c2 = Dw[u * 24 + ((ki >= 2) ? (tb + 2) : (3 + ki))];
    float w0 = (kj == 0) ? I00 : ((kj == 1) ? I01 : I02);
    float w1 = (kj == 0) ? I01 : ((kj == 1) ? I11 : I12);
    float w2 = (kj == 0) ? I02 : ((kj == 1) ? I12 : I22);
    Kw[u * 20 + el] = c0 * w0 + c1 * w1 + c2 * w2;
  }
  if (el < 18) {                          // KS = K * S
    float k0 = Kw[u * 20 + ki * 3], k1 = Kw[u * 20 + ki * 3 + 1], k2 = Kw[u * 20 + ki * 3 + 2];
    float S0 = (kj == 0) ? s00 : ((kj == 1) ? s10 : s20);
    float S1 = (kj == 0) ? s10 : ((kj == 1) ? s11 : s21);
    float S2 = (kj == 0) ? s20 : ((kj == 1) ? s21 : s22);
    KSw[u * 20 + el] = k0 * S0 + k1 * S1 + k2 * S2;
  }

  int s = wid * 2 + u;                    // slot 0..7 == batch bbase+s
  if (el < 6) {                           // xu / xp / yp
    float dbl = Uw[u * 48 + 42 + el];
    float xpl = xbE[el] + dbl;
    float k0 = Kw[u * 20 + el * 3], k1 = Kw[u * 20 + el * 3 + 1], k2 = Kw[u * 20 + el * 3 + 2];
    float xuv = xpl + k0 * i0 + k1 * i1 + k2 * i2;
    if (ebA) {
      outst[0   + s * 6 + el] = xuv;
      outst[336 + s * 6 + el] = xpl;
      if (el < 3) outst[672 + s * 3 + el] = xpl;
    }
  }
  if (el < 9 && ebA) {                    // S full 3x3
    int si = (el >= 6) ? 2 : (el >= 3) ? 1 : 0;
    int sj = el - 3 * si;
    int aa = (si > sj) ? si : sj, bb = (si > sj) ? sj : si;
    int ab = (aa * (aa + 1)) / 2 + bb;
    float sv = (ab == 0) ? s00 : (ab == 1) ? s10 : (ab == 2) ? s11
             : (ab == 3) ? s20 : (ab == 4) ? s21 : s22;
    outst[696 + s * 9 + el] = sv;
  }
  if (el < 18 && ebA) outst[768 + s * 18 + el] = Kw[u * 20 + el];
  if (el < 21) {                          // Pu (and Pp = D + Q), symmetric fill
    float Dv = Dw[u * 24 + el];
    float Qv = qro[el];
    float ks0 = KSw[u * 20 + ti * 3], ks1 = KSw[u * 20 + ti * 3 + 1], ks2 = KSw[u * 20 + ti * 3 + 2];
    float kj0 = Kw[u * 20 + tj * 3],  kj1 = Kw[u * 20 + tj * 3 + 1],  kj2 = Kw[u * 20 + tj * 3 + 2];
    float pu = Dv + Qv - (ks0 * kj0 + ks1 * kj1 + ks2 * kj2) + ((ti == tj) ? 1e-4f : 0.0f);
    float pp = Dv + Qv;
    if (ebA) {
      outst[48  + s * 36 + ti * 6 + tj] = pu;
      outst[48  + s * 36 + tj * 6 + ti] = pu;
      outst[384 + s * 36 + ti * 6 + tj] = pp;
      outst[384 + s * 36 + tj * 6 + ti] = pp;
    }
  }

  __syncthreads();

  // ---- cooperative coalesced output copy: 228 float4 / block ----
  int bbase = blockIdx.x * 8;
  float* o_xu = out;
  float* o_Pu = out + (size_t)6  * B;
  float* o_xp = out + (size_t)42 * B;
  float* o_Pp = out + (size_t)48 * B;
  float* o_yp = out + (size_t)84 * B;
  float* o_S  = out + (size_t)87 * B;
  float* o_K  = out + (size_t)96 * B;
  int t = threadIdx.x;
  if (bbase + 8 <= B && (B & 3) == 0) {   // fast path: all segment bases f4-aligned
    if (t < 228) {
      const float4* ls = (const float4*)outst;
      float4 v = ls[t];
      float4* gp;
      if      (t < 12)  gp = (float4*)(o_xu + (size_t)bbase * 6)  + t;
      else if (t < 84)  gp = (float4*)(o_Pu + (size_t)bbase * 36) + (t - 12);
      else if (t < 96)  gp = (float4*)(o_xp + (size_t)bbase * 6)  + (t - 84);
      else if (t < 168) gp = (float4*)(o_Pp + (size_t)bbase * 36) + (t - 96);
      else if (t < 174) gp = (float4*)(o_yp + (size_t)bbase * 3)  + (t - 168);
      else if (t < 192) gp = (float4*)(o_S  + (size_t)bbase * 9)  + (t - 174);
      else              gp = (float4*)(o_K  + (size_t)bbase * 18) + (t - 192);
      *gp = v;
    }
  } else {                                 // tail block: per-float, bounds-checked
    for (int e = t; e < 912; e += 256) {
      float val = outst[e];
      int r = e, slot; float* gp;
      if (r < 48)        {            slot = r / 6;  gp = o_xu + (size_t)(bbase + slot) * 6  + (r - slot * 6);  }
      else if (r < 336)  { r -= 48;   slot = r / 36; gp = o_Pu + (size_t)(bbase + slot) * 36 + (r - slot * 36); }
      else if (r < 384)  { r -= 336;  slot = r / 6;  gp = o_xp + (size_t)(bbase + slot) * 6  + (r - slot * 6);  }
      else if (r < 672)  { r -= 384;  slot = r / 36; gp = o_Pp + (size_t)(bbase + slot) * 36 + (r - slot * 36); }
      else if (r < 696)  { r -= 672;  slot = r / 3;  gp = o_yp + (size_t)(bbase + slot) * 3  + (r - slot * 3);  }
      else if (r < 768)  { r -= 696;  slot = r / 9;  gp = o_S  + (size_t)(bbase + slot) * 9  + (r - slot * 9);  }
      else               { r -= 768;  slot = r / 18; gp = o_K  + (size_t)(bbase + slot) * 18 + (r - slot * 18); }
      if (bbase + slot < B) *gp = val;
    }
  }
}

extern "C" void kernel_launch(void* const* d_in, const int* in_sizes, int n_in,
                              void* d_out, int out_size, void* d_ws, size_t ws_size,
                              hipStream_t stream) {
  const float* x  = (const float*)d_in[0];
  const float* P  = (const float*)d_in[1];
  const float* u  = (const float*)d_in[2];
  const float* y  = (const float*)d_in[3];
  const float* LQ = (const float*)d_in[4];
  const float* LR = (const float*)d_in[5];
  const float* W1 = (const float*)d_in[6];
  const float* b1 = (const float*)d_in[7];
  const float* W2 = (const float*)d_in[8];
  const float* b2 = (const float*)d_in[9];
  float* out = (float*)d_out;
  char*  ws  = (char*)d_ws;
  int B = in_sizes[0] / 6;

  hipLaunchKernelGGL(prep_small, dim3(1), dim3(64), 0, stream,
                     W1, b1, W2, LQ, LR, ws);
  hipLaunchKernelGGL(ukf_fused, dim3((B + 7) / 8), dim3(256), 0, stream,
                     x, P, u, y, b2, (const char*)ws, out, B);
}